// Round 3
// 148.769 us; speedup vs baseline: 1.0726x; 1.0726x over previous
//
#include <hip/hip_runtime.h>
#include <math.h>

#define B 64
#define C 2048
#define FMH 14
#define HW 196       // 14*14
#define HW4 49       // HW / 4 (float4 columns)
#define CHUNKS 32
#define CPC (C / CHUNKS)   // 64 channels per chunk
#define NWIN 837
#define KMAX 6       // max windows per lane in a group (ceil(361/64))

// clang native vector type — required by __builtin_nontemporal_load
// (HIP_vector_type float4 is rejected; ext_vector_type is accepted and
// supports .x/.y/.z/.w plus elementwise arithmetic).
typedef float f32x4 __attribute__((ext_vector_type(4)));

// Per-ratio tables (RATIOS order from reference)
__device__ __constant__ int d_RH[11]   = {4, 3, 5, 6, 5, 7, 8, 6, 10, 7, 9};
__device__ __constant__ int d_RW[11]   = {4, 5, 3, 6, 7, 5, 8, 10, 6, 9, 7};
__device__ __constant__ int d_WOFF[12] = {0, 121, 241, 361, 442, 522, 602, 651, 696, 741, 789, 837};

// ---------------- Kernel 1: channel reduction ----------------
// x viewed as [B][C][49] f32x4; block (chunk, b) reduces CPC channels of one
// batch into partial[b][chunk][196]. Lane = float4 column (49 of 64 active).
// 4 independent accumulator chains + full unroll: 16 outstanding loads/wave.
// Nontemporal loads on x — read-once stream, don't thrash L2 (the only
// cross-kernel reuse we want cached is the 1.6 MB partial buffer).
// R5 lesson kept: never fuse via per-block agent fences (TCC stall).
__global__ __launch_bounds__(256) void sum_channels_kernel(const f32x4* __restrict__ x,
                                                           f32x4* __restrict__ partial) {
    const int chunk = blockIdx.x;
    const int b     = blockIdx.y;
    const int lane  = threadIdx.x & 63;
    const int wave  = threadIdx.x >> 6;

    f32x4 a0 = (f32x4)(0.f), a1 = (f32x4)(0.f), a2 = (f32x4)(0.f), a3 = (f32x4)(0.f);
    if (lane < HW4) {
        const f32x4* base = x + (size_t)(b * C + chunk * CPC) * HW4 + lane;
        #pragma unroll
        for (int k = 0; k < CPC / 4; k += 4) {   // channel = wave + 4*(k+q)
            f32x4 v0 = __builtin_nontemporal_load(&base[(size_t)(wave + 4 * (k + 0)) * HW4]);
            f32x4 v1 = __builtin_nontemporal_load(&base[(size_t)(wave + 4 * (k + 1)) * HW4]);
            f32x4 v2 = __builtin_nontemporal_load(&base[(size_t)(wave + 4 * (k + 2)) * HW4]);
            f32x4 v3 = __builtin_nontemporal_load(&base[(size_t)(wave + 4 * (k + 3)) * HW4]);
            a0 += v0;
            a1 += v1;
            a2 += v2;
            a3 += v3;
        }
    }
    f32x4 acc = (a0 + a1) + (a2 + a3);

    __shared__ f32x4 sh[256];
    sh[threadIdx.x] = acc;
    __syncthreads();

    if (threadIdx.x < 64 && lane < HW4) {
        f32x4 s = (sh[lane] + sh[64 + lane]) + (sh[128 + lane] + sh[192 + lane]);
        partial[(size_t)(b * CHUNKS + chunk) * HW4 + lane] = s;
    }
}

// ---------------- Kernel 2: one block per batch ----------------
// RESTRUCTURED vs 159.6us version: was one block per (group,batch) = 192
// blocks, each redoing chunk-sum + integral image (3x redundant) with a
// 16-barrier Hillis-Steele scan. Now 64 blocks (one per batch): stage + scan
// once (3 barriers, register-prefix scan), then the 3 groups' NMS run
// wave-parallel (wave g = group g, shfl-only, no barriers).
__device__ inline void decode_box(int w, float& x0, float& y0, float& x1, float& y1, float& area) {
    int r = 0;
    while (w >= d_WOFF[r + 1]) ++r;
    int local = w - d_WOFF[r];
    int rh = d_RH[r], rw = d_RW[r];
    int wc = FMH - rw + 1;
    int i = local / wc, j = local - i * wc;
    x0 = (float)(j * 32);
    y0 = (float)(i * 32);
    x1 = (float)((j + rw) * 32 - 1);
    y1 = (float)((i + rh) * 32 - 1);
    area = (float)(rw * 32) * (float)(rh * 32);
}

__global__ __launch_bounds__(256) void scores_nms_kernel(const float* __restrict__ partial,
                                                         float* __restrict__ out) {
    const int b   = blockIdx.x;   // batch
    const int tid = threadIdx.x;

    __shared__ float S[15][16];   // integral image, padded zero border
    __shared__ float sc[NWIN];    // all 837 window scores for this batch

    // 1) y[hw] = sum over chunk partials (196 threads, coalesced 784B/wave)
    if (tid < HW) {
        const float* p = partial + (size_t)b * CHUNKS * HW + tid;
        float acc = 0.f;
        #pragma unroll
        for (int ch = 0; ch < CHUNKS; ++ch) acc += p[(size_t)ch * HW];
        S[tid / FMH + 1][tid % FMH + 1] = acc;
    }
    if (tid < 16) S[0][tid] = 0.f;
    if (tid < 15) S[tid][0] = 0.f;
    __syncthreads();

    // 2) integral image: 14-thread register-prefix scans.
    //    Issue all 14 LDS reads up front (independent, latency-overlapped),
    //    prefix in registers, write back. Two phases, one barrier each —
    //    replaces 16 Hillis-Steele barrier phases.
    if (tid < FMH) {              // row prefix: thread = row
        float v[FMH];
        #pragma unroll
        for (int j = 0; j < FMH; ++j) v[j] = S[tid + 1][j + 1];
        float a = 0.f;
        #pragma unroll
        for (int j = 0; j < FMH; ++j) { a += v[j]; S[tid + 1][j + 1] = a; }
    }
    __syncthreads();
    if (tid < FMH) {              // column prefix: thread = column
        float v[FMH];
        #pragma unroll
        for (int i = 0; i < FMH; ++i) v[i] = S[i + 1][tid + 1];
        float a = 0.f;
        #pragma unroll
        for (int i = 0; i < FMH; ++i) { a += v[i]; S[i + 1][tid + 1] = a; }
    }
    __syncthreads();

    // 3) all 837 window scores -> LDS + global all_scores (4 iters/thread)
    for (int w = tid; w < NWIN; w += 256) {
        int r = 0;
        while (w >= d_WOFF[r + 1]) ++r;
        int local = w - d_WOFF[r];
        int rh = d_RH[r], rw = d_RW[r];
        int wc = FMH - rw + 1;
        int i = local / wc, j = local - i * wc;
        float s = (S[i + rh][j + rw] - S[i][j + rw] - S[i + rh][j] + S[i][j]) / (float)(rh * rw);
        sc[w] = s;
        out[768 + (size_t)b * NWIN + w] = s;
    }
    __syncthreads();

    // 4) greedy NMS — wave g handles group g, registers + shfl, no barriers
    const int g = tid >> 6;
    if (g >= 3) return;
    const int lane = tid & 63;

    const int GOFFc[3] = {0, 361, 602};
    const int GWc[3]   = {361, 241, 235};
    const int NSELc[3] = {3, 2, 1};
    const int SLOTc[3] = {0, 3, 5};
    const int off = GOFFc[g], W = GWc[g];

    float sv[KMAX], bx0[KMAX], by0[KMAX], bx1[KMAX], by1[KMAX], bar[KMAX];
    unsigned vmask = 0;
    #pragma unroll
    for (int k = 0; k < KMAX; ++k) {
        int wl = lane + 64 * k;
        if (wl < W) {
            sv[k] = sc[off + wl];
            decode_box(off + wl, bx0[k], by0[k], bx1[k], by1[k], bar[k]);
            vmask |= (1u << k);
        } else {
            sv[k] = -INFINITY;
        }
    }

    int last = 0;
    const int nsel = NSELc[g];
    for (int it = 0; it < nsel; ++it) {
        float bv = -INFINITY; int bi = 0x7fffffff;
        #pragma unroll
        for (int k = 0; k < KMAX; ++k) {
            if (vmask & (1u << k)) {
                float v = sv[k];
                int wl = lane + 64 * k;
                if (v > bv || (v == bv && wl < bi)) { bv = v; bi = wl; }
            }
        }
        #pragma unroll
        for (int d = 1; d < 64; d <<= 1) {
            float ov = __shfl_xor(bv, d, 64);
            int   oi = __shfl_xor(bi, d, 64);
            if (ov > bv || (ov == bv && oi < bi)) { bv = ov; bi = oi; }
        }
        const bool any = (bv != -INFINITY);
        const int sel = any ? bi : last;
        last = sel;
        if (lane == 0) {
            out[(size_t)b * 6 + SLOTc[g] + it]       = (float)(off + sel);  // index
            out[384 + (size_t)b * 6 + SLOTc[g] + it] = sc[off + sel];       // score
        }
        if (any) {
            if (it + 1 < nsel) {
                float sx0, sy0, sx1, sy1, sa;
                decode_box(off + sel, sx0, sy0, sx1, sy1, sa);
                #pragma unroll
                for (int k = 0; k < KMAX; ++k) {
                    if (vmask & (1u << k)) {
                        float ltx = fmaxf(bx0[k], sx0), lty = fmaxf(by0[k], sy0);
                        float rbx = fminf(bx1[k], sx1), rby = fminf(by1[k], sy1);
                        float wx = rbx - ltx + 1.f, wy = rby - lty + 1.f;
                        float inter = (wx < 0.f || wy < 0.f) ? 0.f : wx * wy;
                        float iou = inter / (bar[k] + sa - inter);
                        if (iou > 0.25f) vmask &= ~(1u << k);
                    }
                }
            }
            if ((sel & 63) == lane) vmask &= ~(1u << (sel >> 6));
        }
    }
}

extern "C" void kernel_launch(void* const* d_in, const int* in_sizes, int n_in,
                              void* d_out, int out_size, void* d_ws, size_t ws_size,
                              hipStream_t stream) {
    const float* x = (const float*)d_in[0];
    float* out = (float*)d_out;
    float* partial = (float*)d_ws;   // B*CHUNKS*HW floats = 1.6 MB

    sum_channels_kernel<<<dim3(CHUNKS, B), 256, 0, stream>>>((const f32x4*)x, (f32x4*)partial);
    scores_nms_kernel<<<dim3(B), 256, 0, stream>>>(partial, out);
}